// Round 5
// baseline (576.620 us; speedup 1.0000x reference)
//
#include <hip/hip_runtime.h>
#include <hip/hip_bf16.h>

#define NN 8192
#define FIN 256
#define FOUT 64
#define L2E 1.4426950408889634f

typedef __attribute__((ext_vector_type(8))) short short8;
typedef __attribute__((ext_vector_type(4))) float f32x4;
typedef __attribute__((ext_vector_type(4))) int   iv4;

__device__ __forceinline__ unsigned short f2bf(float x){
  unsigned u = __float_as_uint(x);
  u += 0x7FFFu + ((u >> 16) & 1u);      // RTNE
  return (unsigned short)(u >> 16);
}

// ---- k_prep_a: partial Wh = h@W over a k-chunk of 64. lane = row (64 rows/wave),
// W read via uniform (scalar) loads, h staged in LDS with float4 XOR swizzle.
__global__ __launch_bounds__(256) void k_prep_a(const float* __restrict__ h,
    const float* __restrict__ W, float* __restrict__ pWh){
  __shared__ float hs[256][64];   // 64 KB
  const int t = threadIdx.x;
  const int rowbase = (blockIdx.x & 31) * 256;
  const int ks      = blockIdx.x >> 5;
  const int kbase   = ks * 64;
  #pragma unroll
  for (int i = 0; i < 16; ++i){
    int idx = i*256 + t;
    int row = idx >> 4, kq = idx & 15;
    float4 v = *(const float4*)(h + (size_t)(rowbase+row)*FIN + kbase + kq*4);
    *(float4*)&hs[row][(kq ^ (row & 15)) * 4] = v;
  }
  __syncthreads();
  const int l = t & 63, wv = t >> 6;
  const int rr = wv*64 + l;
  float acc[64];
  #pragma unroll
  for (int f = 0; f < 64; ++f) acc[f] = 0.f;
  #pragma unroll 1
  for (int kq = 0; kq < 16; ++kq){
    float4 hv = *(const float4*)&hs[rr][(kq ^ (rr & 15)) * 4];
    const float hj[4] = {hv.x, hv.y, hv.z, hv.w};
    #pragma unroll
    for (int j = 0; j < 4; ++j){
      const float* wrow = W + (size_t)(kbase + kq*4 + j)*FOUT;   // uniform -> s_load
      #pragma unroll
      for (int f = 0; f < 64; ++f)
        acc[f] = fmaf(hj[j], wrow[f], acc[f]);
    }
  }
  float* op = pWh + (size_t)ks*(NN*FOUT) + (size_t)(rowbase + rr)*FOUT;
  #pragma unroll
  for (int f4 = 0; f4 < 16; ++f4)
    *(float4*)(op + f4*4) = *(float4*)&acc[f4*4];
}

// ---- k_prep_b: Wh = sum of 4 partials; emit WhT (bf16 [64][8192]), fsL, fdL
// (pre-scaled by log2 e), gmaxL. wave = one row, lane = feature.
__global__ __launch_bounds__(256) void k_prep_b(const float* __restrict__ pWh,
    const float* __restrict__ a, unsigned short* __restrict__ WhT,
    float* __restrict__ fs, float* __restrict__ fd, unsigned* __restrict__ gmax_u){
  const int t = threadIdx.x, l = t & 63, wv = t >> 6;
  const int row = blockIdx.x*4 + wv;
  const size_t off = (size_t)row*FOUT + l;
  float Wh = pWh[off] + pWh[off + NN*FOUT] + pWh[off + 2*NN*FOUT] + pWh[off + 3*NN*FOUT];
  float p = Wh * a[l], q = Wh * a[64 + l];
  #pragma unroll
  for (int m = 1; m < 64; m <<= 1){
    p += __shfl_xor(p, m); q += __shfl_xor(q, m);
  }
  if (l == 0){
    fs[row] = p * L2E; fd[row] = q * L2E;
    atomicMax(gmax_u, __float_as_uint(q * L2E + 64.0f));   // monotone for >0
  }
  WhT[(size_t)l*NN + row] = f2bf(Wh);
}

// ---- k_attn: wave = 16-row i-tile x split-K/8 chunk (1024 j = 32 steps of 32).
// adj (HBM): 4-deep register prefetch; fdL/WhT (L2): 2-deep. Per line, W-load is
// issued BEFORE adj-load so W-waits leave the newest ABufs in flight.
struct ABuf { iv4 a0, a1; };                              // 8 VGPR
struct WBuf { float4 f0, f1; short8 w0, w1, w2, w3; };    // 24 VGPR

__device__ __forceinline__ void load_adj(ABuf& b, const int* __restrict__ adj,
                                         unsigned a_off, int s){
  const iv4* p = (const iv4*)(adj + a_off + s*32);
  b.a0 = __builtin_nontemporal_load(p);
  b.a1 = __builtin_nontemporal_load(p + 1);
}
__device__ __forceinline__ void load_w(WBuf& b, const float* __restrict__ fd,
    const unsigned short* __restrict__ WhT, unsigned f_off, unsigned w_off, int s){
  b.f0 = *(const float4*)(fd + f_off + s*32);
  b.f1 = *(const float4*)(fd + f_off + s*32 + 4);
  b.w0 = *(const short8*)(WhT + w_off + s*32);
  b.w1 = *(const short8*)(WhT + w_off + s*32 + 16*NN);
  b.w2 = *(const short8*)(WhT + w_off + s*32 + 32*NN);
  b.w3 = *(const short8*)(WhT + w_off + s*32 + 48*NN);
}
__device__ __forceinline__ void step(const ABuf& ab, const WBuf& wb,
    float fsrL, float mL, f32x4* acc, float& s0, float& s1){
  const int   av[8] = {ab.a0.x,ab.a0.y,ab.a0.z,ab.a0.w, ab.a1.x,ab.a1.y,ab.a1.z,ab.a1.w};
  const float fv[8] = {wb.f0.x,wb.f0.y,wb.f0.z,wb.f0.w, wb.f1.x,wb.f1.y,wb.f1.z,wb.f1.w};
  float w[8];
  #pragma unroll
  for (int j = 0; j < 8; ++j){
    float x = fsrL + fv[j];                       // already in log2 domain
    float tt = fmaxf(x, 0.2f*x);                  // leaky_relu (scale-invariant)
    float e  = __builtin_amdgcn_exp2f(tt - mL);   // v_exp_f32
    w[j] = (av[j] != 0) ? e : 0.0f;
  }
  s0 += (w[0]+w[2]) + (w[4]+w[6]);
  s1 += (w[1]+w[3]) + (w[5]+w[7]);
  short8 af;
  __hip_bfloat162* afp = (__hip_bfloat162*)&af;
  #pragma unroll
  for (int j = 0; j < 4; ++j)
    afp[j] = __float22bfloat162_rn(make_float2(w[2*j], w[2*j+1]));
  acc[0] = __builtin_amdgcn_mfma_f32_16x16x32_bf16(af, wb.w0, acc[0], 0,0,0);
  acc[1] = __builtin_amdgcn_mfma_f32_16x16x32_bf16(af, wb.w1, acc[1], 0,0,0);
  acc[2] = __builtin_amdgcn_mfma_f32_16x16x32_bf16(af, wb.w2, acc[2], 0,0,0);
  acc[3] = __builtin_amdgcn_mfma_f32_16x16x32_bf16(af, wb.w3, acc[3], 0,0,0);
}

// Verified layouts (m89/m120): A[m=lane&15][k=(lane>>4)*8+j],
// B[k=(lane>>4)*8+j][n=lane&15], C col=lane&15 row=(lane>>4)*4+reg.
__global__ __launch_bounds__(256, 3) void k_attn(const int* __restrict__ adj,
    const unsigned short* __restrict__ WhT, const float* __restrict__ fs,
    const float* __restrict__ fd, const unsigned* __restrict__ gmax_u,
    float* __restrict__ acc_out, float* __restrict__ s_out){
  const int l = threadIdx.x & 63;
  const int task = blockIdx.x*4 + (threadIdx.x >> 6);  // 4096 wave-tasks
  const int itile = task & 511, kchunk = task >> 9;    // 512 i-tiles x 8 splits
  const int ibase = itile*16, row = l & 15, quad = l >> 4;
  const float gmaxL = __uint_as_float(*gmax_u) - 64.0f;
  const float fsrL  = fs[ibase + row];
  const float xL    = fsrL + gmaxL;
  const float mL    = fmaxf(xL, 0.2f*xL);   // row-max upper bound (leaky monotone)

  const unsigned koff  = (unsigned)kchunk*1024u + quad*8u;
  const unsigned a_off = (unsigned)(ibase+row)*NN + koff;
  const unsigned w_off = (unsigned)row*NN + koff;
  const unsigned f_off = koff;

  f32x4 acc[4];
  #pragma unroll
  for (int nb = 0; nb < 4; ++nb) acc[nb] = (f32x4){0.f,0.f,0.f,0.f};

  ABuf ab0, ab1, ab2, ab3; WBuf wb0, wb1;
  load_w(wb0, fd, WhT, f_off, w_off, 0);
  load_w(wb1, fd, WhT, f_off, w_off, 1);
  load_adj(ab0, adj, a_off, 0); load_adj(ab1, adj, a_off, 1);
  load_adj(ab2, adj, a_off, 2); load_adj(ab3, adj, a_off, 3);

  float s0 = 0.f, s1 = 0.f;
  #pragma unroll 1
  for (int s = 0; s < 28; s += 4){
    step(ab0, wb0, fsrL, mL, acc, s0, s1); load_w(wb0, fd, WhT, f_off, w_off, s+2); load_adj(ab0, adj, a_off, s+4);
    step(ab1, wb1, fsrL, mL, acc, s0, s1); load_w(wb1, fd, WhT, f_off, w_off, s+3); load_adj(ab1, adj, a_off, s+5);
    step(ab2, wb0, fsrL, mL, acc, s0, s1); load_w(wb0, fd, WhT, f_off, w_off, s+4); load_adj(ab2, adj, a_off, s+6);
    step(ab3, wb1, fsrL, mL, acc, s0, s1); load_w(wb1, fd, WhT, f_off, w_off, s+5); load_adj(ab3, adj, a_off, s+7);
  }
  step(ab0, wb0, fsrL, mL, acc, s0, s1); load_w(wb0, fd, WhT, f_off, w_off, 30);
  step(ab1, wb1, fsrL, mL, acc, s0, s1); load_w(wb1, fd, WhT, f_off, w_off, 31);
  step(ab2, wb0, fsrL, mL, acc, s0, s1);
  step(ab3, wb1, fsrL, mL, acc, s0, s1);

  float sacc = s0 + s1;
  sacc += __shfl_xor(sacc, 16);
  sacc += __shfl_xor(sacc, 32);
  if (l < 16) s_out[kchunk*NN + ibase + l] = sacc;
  float* op = acc_out + ((size_t)kchunk*NN + ibase)*FOUT;
  #pragma unroll
  for (int nb = 0; nb < 4; ++nb)
    #pragma unroll
    for (int r = 0; r < 4; ++r)
      op[(quad*4 + r)*FOUT + nb*16 + row] = acc[nb][r];
}

// ---- k_out: combine 8 split-K partials, normalize, ELU.
__global__ __launch_bounds__(256) void k_out(const float* __restrict__ acc,
    const float* __restrict__ s, float* __restrict__ out){
  const int idx = blockIdx.x*256 + threadIdx.x;   // 524288 total
  const int i = idx >> 6;
  float num = 0.f, den = 0.f;
  #pragma unroll
  for (int ks = 0; ks < 8; ++ks){
    num += acc[idx + (size_t)ks*(NN*FOUT)];
    den += s[i + ks*NN];
  }
  float x = num / den;
  out[idx] = (x > 0.f) ? x : (__expf(x) - 1.0f);
}

extern "C" void kernel_launch(void* const* d_in, const int* in_sizes, int n_in,
                              void* d_out, int out_size, void* d_ws, size_t ws_size,
                              hipStream_t stream){
  const float* h   = (const float*)d_in[0];
  const int*   adj = (const int*)d_in[1];
  const float* W   = (const float*)d_in[2];
  const float* a   = (const float*)d_in[3];
  char* ws = (char*)d_ws;
  unsigned short* WhT = (unsigned short*)ws;
  float*    fs     = (float*)(ws + (1u<<20));
  float*    fd     = (float*)(ws + (1u<<20) + 32768);
  unsigned* gmax_u = (unsigned*)(ws + (1u<<20) + 65536);
  float*    pWh    = (float*)(ws + (2u<<20));
  float*    acc    = (float*)(ws + (16u<<20));
  float*    s_ws   = (float*)(ws + (32u<<20));

  (void)hipMemsetAsync(gmax_u, 0, 4, stream);
  k_prep_a<<<128, 256, 0, stream>>>(h, W, pWh);
  k_prep_b<<<2048, 256, 0, stream>>>(pWh, a, WhT, fs, fd, gmax_u);
  k_attn<<<1024, 256, 0, stream>>>(adj, WhT, fs, fd, gmax_u, acc, s_ws);
  k_out<<<2048, 256, 0, stream>>>(acc, s_ws, (float*)d_out);
}

// Round 6
// 524.284 us; speedup vs baseline: 1.0998x; 1.0998x over previous
//
#include <hip/hip_runtime.h>
#include <hip/hip_bf16.h>

#define NN 8192
#define FIN 256
#define FOUT 64
#define L2E 1.4426950408889634f

typedef __attribute__((ext_vector_type(8))) short short8;
typedef __attribute__((ext_vector_type(4))) float f32x4;
typedef __attribute__((ext_vector_type(4))) int   iv4;

__device__ __forceinline__ unsigned short f2bf(float x){
  unsigned u = __float_as_uint(x);
  u += 0x7FFFu + ((u >> 16) & 1u);      // RTNE
  return (unsigned short)(u >> 16);
}

// k_prep (R3-proven): Wh = h@W fp32; fs/fd pre-scaled by log2(e) for exp2-domain
// attention; WhT bf16 [64][8192]; global max of fdL via uint atomicMax(+64 bias).
__global__ __launch_bounds__(256) void k_prep(const float* __restrict__ h,
    const float* __restrict__ W, const float* __restrict__ a,
    unsigned short* __restrict__ WhT, float* __restrict__ fs,
    float* __restrict__ fd, unsigned* __restrict__ gmax_u){
  __shared__ float Ws[128*64];   // 32 KB: half of W (k-tiled)
  __shared__ float hs[8][128];   // 4 KB: 8 rows, k-half
  const int t = threadIdx.x, l = t & 63, wv = t >> 6;
  const int rb = blockIdx.x * 8;            // 8 rows per block, 2 per wave
  float acc0 = 0.f, acc1 = 0.f;
  for (int half = 0; half < 2; ++half){
    if (half) __syncthreads();
    for (int i = t; i < 2048; i += 256)
      ((float4*)Ws)[i] = ((const float4*)W)[half*2048 + i];
    {
      int rr = t >> 5, cc = t & 31;
      ((float4*)&hs[rr][0])[cc] =
          *(const float4*)(h + (size_t)(rb+rr)*FIN + half*128 + cc*4);
    }
    __syncthreads();
    #pragma unroll 8
    for (int k = 0; k < 128; ++k){
      float wval = Ws[k*64 + l];             // lane l = output feature
      acc0 = fmaf(hs[wv*2+0][k], wval, acc0);
      acc1 = fmaf(hs[wv*2+1][k], wval, acc1);
    }
  }
  const int r0 = rb + wv*2, r1 = r0 + 1;
  float a1 = a[l], a2 = a[64 + l];
  float p0 = acc0*a1, q0 = acc0*a2, p1 = acc1*a1, q1 = acc1*a2;
  #pragma unroll
  for (int m = 1; m < 64; m <<= 1){
    p0 += __shfl_xor(p0, m); q0 += __shfl_xor(q0, m);
    p1 += __shfl_xor(p1, m); q1 += __shfl_xor(q1, m);
  }
  if (l == 0){
    fs[r0] = p0*L2E; fs[r1] = p1*L2E; fd[r0] = q0*L2E; fd[r1] = q1*L2E;
    atomicMax(gmax_u, __float_as_uint(q0*L2E + 64.0f));   // monotone for >0
    atomicMax(gmax_u, __float_as_uint(q1*L2E + 64.0f));
  }
  WhT[(size_t)l*NN + r0] = f2bf(acc0);
  WhT[(size_t)l*NN + r1] = f2bf(acc1);
}

// ---- k_attn (R3 skeleton): wave = 16-row i-tile x split-K/4 chunk
// (2048 j = 64 steps of 32). Unified 4-deep named prefetch buffers,
// adj-first issue order, 32-bit offsets off SGPR bases.
struct Buf {
  iv4    a0, a1;          // adj, 8 ints
  float4 f0, f1;          // fdL, 8 floats
  short8 w0, w1, w2, w3;  // WhT B-frags for the 4 n-blocks
};

__device__ __forceinline__ void load_buf(Buf& b, const int* __restrict__ adj,
    unsigned a_off, const float* __restrict__ fd, unsigned f_off,
    const unsigned short* __restrict__ WhT, unsigned w_off, int s){
  const iv4* ap = (const iv4*)(adj + a_off + s*32);
  b.a0 = __builtin_nontemporal_load(ap);
  b.a1 = __builtin_nontemporal_load(ap + 1);
  b.f0 = *(const float4*)(fd + f_off + s*32);
  b.f1 = *(const float4*)(fd + f_off + s*32 + 4);
  b.w0 = *(const short8*)(WhT + w_off + s*32);
  b.w1 = *(const short8*)(WhT + w_off + s*32 + 16*NN);
  b.w2 = *(const short8*)(WhT + w_off + s*32 + 32*NN);
  b.w3 = *(const short8*)(WhT + w_off + s*32 + 48*NN);
}

__device__ __forceinline__ void step_buf(const Buf& b, float fsrL, float mL,
                                         f32x4* acc, float& s0, float& s1){
  const int   av[8] = {b.a0.x,b.a0.y,b.a0.z,b.a0.w, b.a1.x,b.a1.y,b.a1.z,b.a1.w};
  const float fv[8] = {b.f0.x,b.f0.y,b.f0.z,b.f0.w, b.f1.x,b.f1.y,b.f1.z,b.f1.w};
  float w[8];
  #pragma unroll
  for (int j = 0; j < 8; ++j){
    float x  = fsrL + fv[j];                      // log2 domain
    float tt = fmaxf(x, 0.2f*x);                  // leaky_relu (scale-invariant)
    float e  = __builtin_amdgcn_exp2f(tt - mL);   // v_exp_f32
    w[j] = (av[j] != 0) ? e : 0.0f;               // adj mask
  }
  s0 += (w[0]+w[2]) + (w[4]+w[6]);                // two short dep chains
  s1 += (w[1]+w[3]) + (w[5]+w[7]);
  short8 af;
  __hip_bfloat162* afp = (__hip_bfloat162*)&af;
  #pragma unroll
  for (int j = 0; j < 4; ++j)
    afp[j] = __float22bfloat162_rn(make_float2(w[2*j], w[2*j+1]));  // v_cvt_pk_bf16_f32
  acc[0] = __builtin_amdgcn_mfma_f32_16x16x32_bf16(af, b.w0, acc[0], 0,0,0);
  acc[1] = __builtin_amdgcn_mfma_f32_16x16x32_bf16(af, b.w1, acc[1], 0,0,0);
  acc[2] = __builtin_amdgcn_mfma_f32_16x16x32_bf16(af, b.w2, acc[2], 0,0,0);
  acc[3] = __builtin_amdgcn_mfma_f32_16x16x32_bf16(af, b.w3, acc[3], 0,0,0);
}

// Verified layouts (m89/m120): A[m=lane&15][k=(lane>>4)*8+j],
// B[k=(lane>>4)*8+j][n=lane&15], C col=lane&15 row=(lane>>4)*4+reg.
// 512 blocks @ (256,2): 2 blocks/CU, exactly one dispatch round, no tail.
__global__ __launch_bounds__(256, 2) void k_attn(const int* __restrict__ adj,
    const unsigned short* __restrict__ WhT, const float* __restrict__ fs,
    const float* __restrict__ fd, const unsigned* __restrict__ gmax_u,
    float* __restrict__ acc_out, float* __restrict__ s_out){
  const int l = threadIdx.x & 63;
  const int task = blockIdx.x*4 + (threadIdx.x >> 6);  // 2048 wave-tasks
  const int itile = task & 511, kchunk = task >> 9;    // 512 i-tiles x 4 splits
  const int ibase = itile*16, row = l & 15, quad = l >> 4;
  const float gmaxL = __uint_as_float(*gmax_u) - 64.0f;
  const float fsrL  = fs[ibase + row];
  const float xL    = fsrL + gmaxL;
  const float mL    = fmaxf(xL, 0.2f*xL);  // row-max upper bound (leaky monotone)

  const unsigned koff  = (unsigned)kchunk*2048u + quad*8u;
  const unsigned a_off = (unsigned)(ibase+row)*NN + koff;
  const unsigned w_off = (unsigned)row*NN + koff;
  const unsigned f_off = koff;

  f32x4 acc[4];
  #pragma unroll
  for (int nb = 0; nb < 4; ++nb) acc[nb] = (f32x4){0.f,0.f,0.f,0.f};

  Buf b0, b1, b2, b3;
  load_buf(b0, adj, a_off, fd, f_off, WhT, w_off, 0);
  load_buf(b1, adj, a_off, fd, f_off, WhT, w_off, 1);
  load_buf(b2, adj, a_off, fd, f_off, WhT, w_off, 2);
  load_buf(b3, adj, a_off, fd, f_off, WhT, w_off, 3);

  float s0 = 0.f, s1 = 0.f;
  #pragma unroll 1
  for (int s = 0; s < 64; s += 4){
    step_buf(b0, fsrL, mL, acc, s0, s1);
    if (s+4 < 64) load_buf(b0, adj, a_off, fd, f_off, WhT, w_off, s+4);
    step_buf(b1, fsrL, mL, acc, s0, s1);
    if (s+5 < 64) load_buf(b1, adj, a_off, fd, f_off, WhT, w_off, s+5);
    step_buf(b2, fsrL, mL, acc, s0, s1);
    if (s+6 < 64) load_buf(b2, adj, a_off, fd, f_off, WhT, w_off, s+6);
    step_buf(b3, fsrL, mL, acc, s0, s1);
    if (s+7 < 64) load_buf(b3, adj, a_off, fd, f_off, WhT, w_off, s+7);
  }

  float sacc = s0 + s1;
  sacc += __shfl_xor(sacc, 16);
  sacc += __shfl_xor(sacc, 32);
  if (l < 16) s_out[kchunk*NN + ibase + l] = sacc;
  float* op = acc_out + ((size_t)kchunk*NN + ibase)*FOUT;
  #pragma unroll
  for (int nb = 0; nb < 4; ++nb)
    #pragma unroll
    for (int r = 0; r < 4; ++r)
      op[(quad*4 + r)*FOUT + nb*16 + row] = acc[nb][r];
}

// ---- k_out: combine 4 split-K partials, normalize, ELU.
__global__ __launch_bounds__(256) void k_out(const float* __restrict__ acc,
    const float* __restrict__ s, float* __restrict__ out){
  const int idx = blockIdx.x*256 + threadIdx.x;   // 524288 total
  const int i = idx >> 6;
  float num = acc[idx] + acc[idx + NN*FOUT] + acc[idx + 2*NN*FOUT] + acc[idx + 3*NN*FOUT];
  float den = s[i] + s[i + NN] + s[i + 2*NN] + s[i + 3*NN];
  float x = num / den;
  out[idx] = (x > 0.f) ? x : (__expf(x) - 1.0f);
}

extern "C" void kernel_launch(void* const* d_in, const int* in_sizes, int n_in,
                              void* d_out, int out_size, void* d_ws, size_t ws_size,
                              hipStream_t stream){
  const float* h   = (const float*)d_in[0];
  const int*   adj = (const int*)d_in[1];
  const float* W   = (const float*)d_in[2];
  const float* a   = (const float*)d_in[3];
  char* ws = (char*)d_ws;
  // ws: [0,1M) WhT | 1M fs | 1M+32K fd | 1M+64K gmax | [2M,10M) acc x4 | 10M s x4
  unsigned short* WhT = (unsigned short*)ws;
  float*    fs     = (float*)(ws + (1u<<20));
  float*    fd     = (float*)(ws + (1u<<20) + 32768);
  unsigned* gmax_u = (unsigned*)(ws + (1u<<20) + 65536);
  float*    acc    = (float*)(ws + (2u<<20));
  float*    s_ws   = (float*)(ws + (10u<<20));

  (void)hipMemsetAsync(gmax_u, 0, 4, stream);
  k_prep<<<1024, 256, 0, stream>>>(h, W, a, WhT, fs, fd, gmax_u);
  k_attn<<<512, 256, 0, stream>>>(adj, WhT, fs, fd, gmax_u, acc, s_ws);
  k_out<<<2048, 256, 0, stream>>>(acc, s_ws, (float*)d_out);
}

// Round 7
// 520.646 us; speedup vs baseline: 1.1075x; 1.0070x over previous
//
#include <hip/hip_runtime.h>
#include <hip/hip_bf16.h>

#define NN 8192
#define FIN 256
#define FOUT 64
#define L2E 1.4426950408889634f

typedef __attribute__((ext_vector_type(8))) short short8;
typedef __attribute__((ext_vector_type(4))) float f32x4;
typedef __attribute__((ext_vector_type(4))) int   iv4;

__device__ __forceinline__ unsigned short f2bf(float x){
  unsigned u = __float_as_uint(x);
  u += 0x7FFFu + ((u >> 16) & 1u);      // RTNE
  return (unsigned short)(u >> 16);
}

// k_prep: Wh = h@W fp32; fs/fd pre-scaled by log2(e); WhT bf16 [64][8192];
// global max of fdL via uint atomicMax(+64 bias, monotone for positives).
__global__ __launch_bounds__(256) void k_prep(const float* __restrict__ h,
    const float* __restrict__ W, const float* __restrict__ a,
    unsigned short* __restrict__ WhT, float* __restrict__ fs,
    float* __restrict__ fd, unsigned* __restrict__ gmax_u){
  __shared__ float Ws[128*64];   // 32 KB: half of W (k-tiled)
  __shared__ float hs[8][128];   // 4 KB: 8 rows, k-half
  const int t = threadIdx.x, l = t & 63, wv = t >> 6;
  const int rb = blockIdx.x * 8;            // 8 rows per block, 2 per wave
  float acc0 = 0.f, acc1 = 0.f;
  for (int half = 0; half < 2; ++half){
    if (half) __syncthreads();
    for (int i = t; i < 2048; i += 256)
      ((float4*)Ws)[i] = ((const float4*)W)[half*2048 + i];
    {
      int rr = t >> 5, cc = t & 31;
      ((float4*)&hs[rr][0])[cc] =
          *(const float4*)(h + (size_t)(rb+rr)*FIN + half*128 + cc*4);
    }
    __syncthreads();
    #pragma unroll 8
    for (int k = 0; k < 128; ++k){
      float wval = Ws[k*64 + l];             // lane l = output feature
      acc0 = fmaf(hs[wv*2+0][k], wval, acc0);
      acc1 = fmaf(hs[wv*2+1][k], wval, acc1);
    }
  }
  const int r0 = rb + wv*2, r1 = r0 + 1;
  float a1 = a[l], a2 = a[64 + l];
  float p0 = acc0*a1, q0 = acc0*a2, p1 = acc1*a1, q1 = acc1*a2;
  #pragma unroll
  for (int m = 1; m < 64; m <<= 1){
    p0 += __shfl_xor(p0, m); q0 += __shfl_xor(q0, m);
    p1 += __shfl_xor(p1, m); q1 += __shfl_xor(q1, m);
  }
  if (l == 0){
    fs[r0] = p0*L2E; fs[r1] = p1*L2E; fd[r0] = q0*L2E; fd[r1] = q1*L2E;
    atomicMax(gmax_u, __float_as_uint(q0*L2E + 64.0f));
    atomicMax(gmax_u, __float_as_uint(q1*L2E + 64.0f));
  }
  WhT[(size_t)l*NN + r0] = f2bf(acc0);
  WhT[(size_t)l*NN + r1] = f2bf(acc1);
}

// ---- k_attn: wave = 16-row i-tile x split-K/8 chunk (1024 j = 32 steps of 32).
// 2-deep named prefetch buffers (low VGPR) + (256,4) -> 16 waves/CU: TLP covers
// the vmcnt stalls instead of deep per-wave ILP. 1024 blocks @ 4/CU: tail-free.
struct Buf {
  iv4    a0, a1;          // adj, 8 ints
  float4 f0, f1;          // fdL, 8 floats
  short8 w0, w1, w2, w3;  // WhT B-frags for the 4 n-blocks
};

__device__ __forceinline__ void load_buf(Buf& b, const int* __restrict__ adj,
    unsigned a_off, const float* __restrict__ fd, unsigned f_off,
    const unsigned short* __restrict__ WhT, unsigned w_off, int s){
  const iv4* ap = (const iv4*)(adj + a_off + s*32);
  b.a0 = __builtin_nontemporal_load(ap);
  b.a1 = __builtin_nontemporal_load(ap + 1);
  b.f0 = *(const float4*)(fd + f_off + s*32);
  b.f1 = *(const float4*)(fd + f_off + s*32 + 4);
  b.w0 = *(const short8*)(WhT + w_off + s*32);
  b.w1 = *(const short8*)(WhT + w_off + s*32 + 16*NN);
  b.w2 = *(const short8*)(WhT + w_off + s*32 + 32*NN);
  b.w3 = *(const short8*)(WhT + w_off + s*32 + 48*NN);
}

__device__ __forceinline__ void step_buf(const Buf& b, float fsrL, float mL,
                                         f32x4* acc, float& s0, float& s1){
  const int   av[8] = {b.a0.x,b.a0.y,b.a0.z,b.a0.w, b.a1.x,b.a1.y,b.a1.z,b.a1.w};
  const float fv[8] = {b.f0.x,b.f0.y,b.f0.z,b.f0.w, b.f1.x,b.f1.y,b.f1.z,b.f1.w};
  float w[8];
  #pragma unroll
  for (int j = 0; j < 8; ++j){
    float x  = fsrL + fv[j];                      // log2 domain
    float tt = fmaxf(x, 0.2f*x);                  // leaky_relu (scale-invariant)
    float e  = __builtin_amdgcn_exp2f(tt - mL);   // v_exp_f32
    w[j] = (av[j] != 0) ? e : 0.0f;               // adj mask
  }
  s0 += (w[0]+w[2]) + (w[4]+w[6]);
  s1 += (w[1]+w[3]) + (w[5]+w[7]);
  short8 af;
  __hip_bfloat162* afp = (__hip_bfloat162*)&af;
  #pragma unroll
  for (int j = 0; j < 4; ++j)
    afp[j] = __float22bfloat162_rn(make_float2(w[2*j], w[2*j+1]));  // v_cvt_pk_bf16_f32
  acc[0] = __builtin_amdgcn_mfma_f32_16x16x32_bf16(af, b.w0, acc[0], 0,0,0);
  acc[1] = __builtin_amdgcn_mfma_f32_16x16x32_bf16(af, b.w1, acc[1], 0,0,0);
  acc[2] = __builtin_amdgcn_mfma_f32_16x16x32_bf16(af, b.w2, acc[2], 0,0,0);
  acc[3] = __builtin_amdgcn_mfma_f32_16x16x32_bf16(af, b.w3, acc[3], 0,0,0);
}

// Verified layouts (m89/m120): A[m=lane&15][k=(lane>>4)*8+j],
// B[k=(lane>>4)*8+j][n=lane&15], C col=lane&15 row=(lane>>4)*4+reg.
__global__ __launch_bounds__(256, 4) void k_attn(const int* __restrict__ adj,
    const unsigned short* __restrict__ WhT, const float* __restrict__ fs,
    const float* __restrict__ fd, const unsigned* __restrict__ gmax_u,
    float* __restrict__ acc_out, float* __restrict__ s_out){
  const int l = threadIdx.x & 63;
  const int task = blockIdx.x*4 + (threadIdx.x >> 6);  // 4096 wave-tasks
  const int itile = task & 511, kchunk = task >> 9;    // 512 i-tiles x 8 splits
  const int ibase = itile*16, row = l & 15, quad = l >> 4;
  const float gmaxL = __uint_as_float(*gmax_u) - 64.0f;
  const float fsrL  = fs[ibase + row];
  const float xL    = fsrL + gmaxL;
  const float mL    = fmaxf(xL, 0.2f*xL);  // row-max upper bound (leaky monotone)

  const unsigned koff  = (unsigned)kchunk*1024u + quad*8u;
  const unsigned a_off = (unsigned)(ibase+row)*NN + koff;
  const unsigned w_off = (unsigned)row*NN + koff;
  const unsigned f_off = koff;

  f32x4 acc[4];
  #pragma unroll
  for (int nb = 0; nb < 4; ++nb) acc[nb] = (f32x4){0.f,0.f,0.f,0.f};

  Buf b0, b1;
  load_buf(b0, adj, a_off, fd, f_off, WhT, w_off, 0);
  load_buf(b1, adj, a_off, fd, f_off, WhT, w_off, 1);

  float s0 = 0.f, s1 = 0.f;
  #pragma unroll 1
  for (int s = 0; s < 32; s += 2){
    step_buf(b0, fsrL, mL, acc, s0, s1);
    if (s+2 < 32) load_buf(b0, adj, a_off, fd, f_off, WhT, w_off, s+2);
    step_buf(b1, fsrL, mL, acc, s0, s1);
    if (s+3 < 32) load_buf(b1, adj, a_off, fd, f_off, WhT, w_off, s+3);
  }

  float sacc = s0 + s1;
  sacc += __shfl_xor(sacc, 16);
  sacc += __shfl_xor(sacc, 32);
  if (l < 16) s_out[kchunk*NN + ibase + l] = sacc;
  float* op = acc_out + ((size_t)kchunk*NN + ibase)*FOUT;
  #pragma unroll
  for (int nb = 0; nb < 4; ++nb)
    #pragma unroll
    for (int r = 0; r < 4; ++r)
      op[(quad*4 + r)*FOUT + nb*16 + row] = acc[nb][r];
}

// ---- k_out: combine 8 split-K partials, normalize, ELU.
__global__ __launch_bounds__(256) void k_out(const float* __restrict__ acc,
    const float* __restrict__ s, float* __restrict__ out){
  const int idx = blockIdx.x*256 + threadIdx.x;   // 524288 total
  const int i = idx >> 6;
  float num = 0.f, den = 0.f;
  #pragma unroll
  for (int ks = 0; ks < 8; ++ks){
    num += acc[idx + (size_t)ks*(NN*FOUT)];
    den += s[i + ks*NN];
  }
  float x = num / den;
  out[idx] = (x > 0.f) ? x : (__expf(x) - 1.0f);
}

extern "C" void kernel_launch(void* const* d_in, const int* in_sizes, int n_in,
                              void* d_out, int out_size, void* d_ws, size_t ws_size,
                              hipStream_t stream){
  const float* h   = (const float*)d_in[0];
  const int*   adj = (const int*)d_in[1];
  const float* W   = (const float*)d_in[2];
  const float* a   = (const float*)d_in[3];
  char* ws = (char*)d_ws;
  // ws: [0,1M) WhT | 1M fs | 1M+32K fd | 1M+64K gmax | [2M,18M) acc x8 | 20M s x8
  unsigned short* WhT = (unsigned short*)ws;
  float*    fs     = (float*)(ws + (1u<<20));
  float*    fd     = (float*)(ws + (1u<<20) + 32768);
  unsigned* gmax_u = (unsigned*)(ws + (1u<<20) + 65536);
  float*    acc    = (float*)(ws + (2u<<20));
  float*    s_ws   = (float*)(ws + (20u<<20));

  (void)hipMemsetAsync(gmax_u, 0, 4, stream);
  k_prep<<<1024, 256, 0, stream>>>(h, W, a, WhT, fs, fd, gmax_u);
  k_attn<<<1024, 256, 0, stream>>>(adj, WhT, fs, fd, gmax_u, acc, s_ws);
  k_out<<<2048, 256, 0, stream>>>(acc, s_ws, (float*)d_out);
}